// Round 4
// baseline (3831.969 us; speedup 1.0000x reference)
//
#include <hip/hip_runtime.h>

typedef unsigned int u32;
typedef unsigned short u16;

#define NPTS 65536
#define DMODEL 256
#define NHEAD 8
#define DHEAD 32
#define NLAYER 4
#define FFDIM 2048
#define WSIZE 128
#define LNEPS 1e-5f
#define RG 256  // radix sort blocks (chunk = 256 elements each)

typedef __attribute__((ext_vector_type(8))) short short8;
typedef __attribute__((ext_vector_type(4))) float floatx4;

__device__ __forceinline__ float bf2f(u16 v) {
    u32 u = ((u32)v) << 16;
    float f;
    __builtin_memcpy(&f, &u, 4);
    return f;
}
__device__ __forceinline__ u16 f2bf(float f) {
    u32 u;
    __builtin_memcpy(&u, &f, 4);
    u32 r = (u + 0x7fffu + ((u >> 16) & 1u)) >> 16;
    return (u16)r;
}

__device__ __forceinline__ void gl_lds16(const void* g, void* l) {
    __builtin_amdgcn_global_load_lds((const __attribute__((address_space(1))) u32*)g,
                                     (__attribute__((address_space(3))) u32*)l, 16, 0, 0);
}

// ---------------- Morton keys ----------------
__global__ __launch_bounds__(256) void morton_kernel(const int* __restrict__ coords,
                                                     u32* __restrict__ key, u32* __restrict__ val) {
    int i = blockIdx.x * 256 + threadIdx.x;
    int b = coords[4 * i + 0];
    int x = coords[4 * i + 1];
    int y = coords[4 * i + 2];
    int z = coords[4 * i + 3];
    u32 m = 0;
#pragma unroll
    for (int t = 0; t < 7; ++t) {
        m |= ((u32)((x >> t) & 1) << (3 * t + 2)) | ((u32)((y >> t) & 1) << (3 * t + 1)) |
             ((u32)((z >> t) & 1) << (3 * t));
    }
    key[i] = ((u32)b << 21) | m;
    val[i] = (u32)i;
}

// ---------------- radix sort (stable LSD, 3 x 8-bit) ----------------
__global__ __launch_bounds__(256) void hist_kernel(const u32* __restrict__ key, u32* __restrict__ ghist,
                                                   int shift) {
    __shared__ u32 h[256];
    int tid = threadIdx.x;
    h[tid] = 0;
    __syncthreads();
    u32 k = key[blockIdx.x * 256 + tid];
    atomicAdd(&h[(k >> shift) & 255u], 1u);
    __syncthreads();
    ghist[(size_t)tid * RG + blockIdx.x] = h[tid];  // bucket-major
}

__global__ __launch_bounds__(1024) void scan_kernel(u32* __restrict__ g) {
    // exclusive scan over 256*RG = 65536 entries, single block
    __shared__ u32 part[1024];
    int tid = threadIdx.x;
    u32 loc[64];
    u32 s = 0;
    int base = tid * 64;
#pragma unroll 4
    for (int i = 0; i < 64; ++i) {
        loc[i] = g[base + i];
        s += loc[i];
    }
    part[tid] = s;
    __syncthreads();
    for (int off = 1; off < 1024; off <<= 1) {
        u32 v = (tid >= off) ? part[tid - off] : 0u;
        __syncthreads();
        part[tid] += v;
        __syncthreads();
    }
    u32 run = (tid == 0) ? 0u : part[tid - 1];
#pragma unroll 4
    for (int i = 0; i < 64; ++i) {
        u32 t = loc[i];
        g[base + i] = run;
        run += t;
    }
}

__global__ __launch_bounds__(256) void scatter_kernel(const u32* __restrict__ keyin, const u32* __restrict__ valin,
                                                      u32* __restrict__ keyout, u32* __restrict__ valout,
                                                      const u32* __restrict__ ghist, int shift) {
    __shared__ u32 kk[256];
    __shared__ u32 vv[256];
    int tid = threadIdx.x;
    int gi = blockIdx.x * 256 + tid;
    kk[tid] = keyin[gi];
    vv[tid] = valin[gi];
    __syncthreads();
    u32 b = (kk[tid] >> shift) & 255u;
    int rank = 0;
    for (int s = 0; s < tid; ++s) rank += (((kk[s] >> shift) & 255u) == b) ? 1 : 0;
    u32 dst = ghist[(size_t)b * RG + blockIdx.x] + (u32)rank;
    keyout[dst] = kk[tid];
    valout[dst] = vv[tid];
}

// ---------------- weight fp32 -> bf16 ----------------
__global__ __launch_bounds__(256) void cvt_bf16_kernel(const float* __restrict__ in, u16* __restrict__ out, int n) {
    int i = blockIdx.x * 256 + threadIdx.x;
    if (i < n) out[i] = f2bf(in[i]);
}

// ---------------- gather + positional encodings ----------------
template <bool HF32>
__global__ __launch_bounds__(256) void gather_pe_kernel(const u32* __restrict__ idx, const int* __restrict__ coords,
                                                        const float* __restrict__ feat,
                                                        const float* __restrict__ pex, const float* __restrict__ pey,
                                                        const float* __restrict__ pez, const float* __restrict__ pes,
                                                        float* __restrict__ h, u16* __restrict__ xb) {
    int row = blockIdx.x * 4 + (threadIdx.x >> 6);
    int lane = threadIdx.x & 63;
    int src = (int)idx[row];
    int cx = coords[4 * src + 1];
    int cy = coords[4 * src + 2];
    int cz = coords[4 * src + 3];
    int c = lane * 4;
    float4 f = *(const float4*)(feat + (size_t)src * DMODEL + c);
    float4 px = *(const float4*)(pex + (size_t)cx * DMODEL + c);
    float4 py = *(const float4*)(pey + (size_t)cy * DMODEL + c);
    float4 pz = *(const float4*)(pez + (size_t)cz * DMODEL + c);
    float4 ps = *(const float4*)(pes + (size_t)1 * DMODEL + c);  // pe_s[1]
    float4 r;
    r.x = f.x + px.x + py.x + pz.x + ps.x;
    r.y = f.y + px.y + py.y + pz.y + ps.y;
    r.z = f.z + px.z + py.z + pz.z + ps.z;
    r.w = f.w + px.w + py.w + pz.w + ps.w;
    if (HF32) *(float4*)(h + (size_t)row * DMODEL + c) = r;
    ushort4 o;
    o.x = f2bf(r.x);
    o.y = f2bf(r.y);
    o.z = f2bf(r.z);
    o.w = f2bf(r.w);
    *(ushort4*)(xb + (size_t)row * DMODEL + c) = o;
}

// ---------------- GEMM: C = A @ W^T + bias  (A: MxK bf16, W: OxK bf16) ----------------
// m97-style: 128x128 tile, BK=64, 4 waves each computing 64x64 via 4x4 of 16x16x32 MFMA.
template <bool RELU, bool BF16OUT>
__global__ __launch_bounds__(256) void gemm_bt(const u16* __restrict__ A, const u16* __restrict__ W,
                                               const float* __restrict__ bias, void* __restrict__ Cout,
                                               int M, int O, int K) {
    __shared__ __align__(16) u16 lA[128 * 64];
    __shared__ __align__(16) u16 lB[128 * 64];
    const int tid = threadIdx.x;
    const int lane = tid & 63;
    const int wave = tid >> 6;
    const int wr = wave >> 1;
    const int wc = wave & 1;
    const int quad = lane >> 4;
    const int l16 = lane & 15;
    const size_t row0 = (size_t)blockIdx.x * 128;
    const size_t col0 = (size_t)blockIdx.y * 128;
    floatx4 acc[4][4] = {};
    const u16* Abase = A + row0 * (size_t)K;
    const u16* Wbase = W + col0 * (size_t)K;

    for (int k0 = 0; k0 < K; k0 += 64) {
        __syncthreads();
#pragma unroll
        for (int it = 0; it < 4; ++it) {
            int cidx = tid + it * 256;   // chunk 0..1023; each chunk = 8 bf16 = 16B
            int r = cidx >> 3;           // row 0..127
            int cc = (cidx & 7) << 3;    // col 0..56 step 8
            gl_lds16(Abase + (size_t)r * K + k0 + cc, &lA[cidx * 8]);
            gl_lds16(Wbase + (size_t)r * K + k0 + cc, &lB[cidx * 8]);
        }
        __syncthreads();
#pragma unroll
        for (int kk = 0; kk < 64; kk += 32) {
            short8 af[4], bf[4];
#pragma unroll
            for (int r = 0; r < 4; ++r)
                af[r] = *(const short8*)&lA[(wr * 64 + r * 16 + l16) * 64 + kk + quad * 8];
#pragma unroll
            for (int c = 0; c < 4; ++c)
                bf[c] = *(const short8*)&lB[(wc * 64 + c * 16 + l16) * 64 + kk + quad * 8];
#pragma unroll
            for (int r = 0; r < 4; ++r)
#pragma unroll
                for (int c = 0; c < 4; ++c)
                    acc[r][c] = __builtin_amdgcn_mfma_f32_16x16x32_bf16(af[r], bf[c], acc[r][c], 0, 0, 0);
        }
    }

#pragma unroll
    for (int r = 0; r < 4; ++r) {
#pragma unroll
        for (int c = 0; c < 4; ++c) {
            size_t col = col0 + wc * 64 + c * 16 + l16;
            float bv = bias[col];
#pragma unroll
            for (int reg = 0; reg < 4; ++reg) {
                size_t row = row0 + wr * 64 + r * 16 + quad * 4 + reg;
                float v = acc[r][c][reg] + bv;
                if (RELU) v = fmaxf(v, 0.f);
                if (BF16OUT)
                    ((u16*)Cout)[row * O + col] = f2bf(v);
                else
                    ((float*)Cout)[row * O + col] = v;
            }
        }
    }
}

// ---------------- window attention (one block = one (window, head)) ----------------
// Two-pass softmax, no per-thread score array (round-3 version spilled 128 MB/dispatch
// of scratch traffic: s[128] per thread -> FETCH 89MB/WRITE 139MB vs ideal 25/8).
__global__ __launch_bounds__(128) void attn_kernel(const u16* __restrict__ qkv, u16* __restrict__ outb) {
    int wh = blockIdx.x;
    int w = wh >> 3;   // window index within chunk
    int h = wh & 7;
    int tid = threadIdx.x;  // my query row in window
    __shared__ float kk[WSIZE * DHEAD];
    __shared__ float vv[WSIZE * DHEAD];
    const u16* base = qkv + (size_t)w * WSIZE * (3 * DMODEL);
    {
        const u16* krow = base + (size_t)tid * (3 * DMODEL) + DMODEL + h * DHEAD;
        const u16* vrow = base + (size_t)tid * (3 * DMODEL) + 2 * DMODEL + h * DHEAD;
#pragma unroll
        for (int d4 = 0; d4 < DHEAD / 4; ++d4) {
            ushort4 kv = *(const ushort4*)(krow + d4 * 4);
            ushort4 vv4 = *(const ushort4*)(vrow + d4 * 4);
            kk[tid * DHEAD + d4 * 4 + 0] = bf2f(kv.x);
            kk[tid * DHEAD + d4 * 4 + 1] = bf2f(kv.y);
            kk[tid * DHEAD + d4 * 4 + 2] = bf2f(kv.z);
            kk[tid * DHEAD + d4 * 4 + 3] = bf2f(kv.w);
            vv[tid * DHEAD + d4 * 4 + 0] = bf2f(vv4.x);
            vv[tid * DHEAD + d4 * 4 + 1] = bf2f(vv4.y);
            vv[tid * DHEAD + d4 * 4 + 2] = bf2f(vv4.z);
            vv[tid * DHEAD + d4 * 4 + 3] = bf2f(vv4.w);
        }
    }
    const float scale = 0.17677669529663687f;  // 1/sqrt(32)
    float q[DHEAD];
    {
        const u16* qrow = base + (size_t)tid * (3 * DMODEL) + h * DHEAD;
#pragma unroll
        for (int d4 = 0; d4 < DHEAD / 4; ++d4) {
            ushort4 qv = *(const ushort4*)(qrow + d4 * 4);
            q[d4 * 4 + 0] = bf2f(qv.x) * scale;
            q[d4 * 4 + 1] = bf2f(qv.y) * scale;
            q[d4 * 4 + 2] = bf2f(qv.z) * scale;
            q[d4 * 4 + 3] = bf2f(qv.w) * scale;
        }
    }
    __syncthreads();
    // pass 1: row max
    float mx = -3.4e38f;
    for (int j = 0; j < WSIZE; ++j) {
        float a = 0.f;
#pragma unroll
        for (int d = 0; d < DHEAD; ++d) a += q[d] * kk[j * DHEAD + d];
        mx = fmaxf(mx, a);
    }
    // pass 2: exp-sum + weighted V accumulate (scores recomputed, nothing stored)
    float sum = 0.f;
    float o[DHEAD] = {};
    for (int j = 0; j < WSIZE; ++j) {
        float a = 0.f;
#pragma unroll
        for (int d = 0; d < DHEAD; ++d) a += q[d] * kk[j * DHEAD + d];
        float e = __expf(a - mx);
        sum += e;
#pragma unroll
        for (int d = 0; d < DHEAD; ++d) o[d] += e * vv[j * DHEAD + d];
    }
    float inv = 1.f / sum;
    u16* orow = outb + (size_t)(w * WSIZE + tid) * DMODEL + h * DHEAD;
#pragma unroll
    for (int d4 = 0; d4 < DHEAD / 4; ++d4) {
        ushort4 ov;
        ov.x = f2bf(o[d4 * 4 + 0] * inv);
        ov.y = f2bf(o[d4 * 4 + 1] * inv);
        ov.z = f2bf(o[d4 * 4 + 2] * inv);
        ov.w = f2bf(o[d4 * 4 + 3] * inv);
        *(ushort4*)(orow + d4 * 4) = ov;
    }
}

// ---------------- residual add + LayerNorm (chunk-local, pointers pre-offset) ----------------
// HF32: residual stream held in fp32 (hin/hout) vs bf16 (hin bf16, no hout)
// OUTF32: normalized output written as fp32 (final layer -> d_out) vs bf16
template <bool HF32, bool OUTF32>
__global__ __launch_bounds__(256) void resid_ln_kernel(const void* __restrict__ hin, const float* __restrict__ delta,
                                                       const float* __restrict__ g, const float* __restrict__ b,
                                                       float* __restrict__ hout, void* __restrict__ nout) {
    int row = blockIdx.x * 4 + (threadIdx.x >> 6);
    int lane = threadIdx.x & 63;
    int c = lane * 4;
    float4 x;
    if (HF32) {
        x = *(const float4*)((const float*)hin + (size_t)row * DMODEL + c);
    } else {
        ushort4 hv = *(const ushort4*)((const u16*)hin + (size_t)row * DMODEL + c);
        x.x = bf2f(hv.x);
        x.y = bf2f(hv.y);
        x.z = bf2f(hv.z);
        x.w = bf2f(hv.w);
    }
    float4 d = *(const float4*)(delta + (size_t)row * DMODEL + c);
    x.x += d.x;
    x.y += d.y;
    x.z += d.z;
    x.w += d.w;
    float s = x.x + x.y + x.z + x.w;
#pragma unroll
    for (int off = 32; off > 0; off >>= 1) s += __shfl_xor(s, off, 64);
    float mu = s * (1.f / 256.f);
    float d0 = x.x - mu, d1 = x.y - mu, d2 = x.z - mu, d3 = x.w - mu;
    float vs = d0 * d0 + d1 * d1 + d2 * d2 + d3 * d3;
#pragma unroll
    for (int off = 32; off > 0; off >>= 1) vs += __shfl_xor(vs, off, 64);
    float rs = rsqrtf(vs * (1.f / 256.f) + LNEPS);
    float4 gg = *(const float4*)(g + c);
    float4 bb = *(const float4*)(b + c);
    float4 y;
    y.x = d0 * rs * gg.x + bb.x;
    y.y = d1 * rs * gg.y + bb.y;
    y.z = d2 * rs * gg.z + bb.z;
    y.w = d3 * rs * gg.w + bb.w;
    if (HF32) *(float4*)(hout + (size_t)row * DMODEL + c) = y;
    if (OUTF32) {
        *(float4*)((float*)nout + (size_t)row * DMODEL + c) = y;
    } else {
        ushort4 o;
        o.x = f2bf(y.x);
        o.y = f2bf(y.y);
        o.z = f2bf(y.z);
        o.w = f2bf(y.w);
        *(ushort4*)((u16*)nout + (size_t)row * DMODEL + c) = o;
    }
}

// ---------------- launch ----------------
extern "C" void kernel_launch(void* const* d_in, const int* in_sizes, int n_in,
                              void* d_out, int out_size, void* d_ws, size_t ws_size,
                              hipStream_t stream) {
    (void)in_sizes;
    (void)n_in;
    (void)out_size;
    const int* coords = (const int*)d_in[0];
    const float* feat = (const float*)d_in[1];
    const float* pex = (const float*)d_in[2];
    const float* pey = (const float*)d_in[3];
    const float* pez = (const float*)d_in[4];
    const float* pes = (const float*)d_in[5];
    const float* Wqkv = (const float*)d_in[6];
    const float* bqkv = (const float*)d_in[7];
    const float* Wo = (const float*)d_in[8];
    const float* bo = (const float*)d_in[9];
    const float* W1 = (const float*)d_in[10];
    const float* b1 = (const float*)d_in[11];
    const float* W2 = (const float*)d_in[12];
    const float* b2 = (const float*)d_in[13];
    const float* g1 = (const float*)d_in[14];
    const float* be1 = (const float*)d_in[15];
    const float* g2 = (const float*)d_in[16];
    const float* be2 = (const float*)d_in[17];

    auto al = [](size_t x) { return (x + 255) & ~(size_t)255; };
    // fixed allocations
    const size_t sortB = 4 * al((size_t)NPTS * 4) + al((size_t)256 * RG * 4);
    const size_t wqkvB = al((size_t)NLAYER * 3 * DMODEL * DMODEL * 2);
    const size_t woB = al((size_t)NLAYER * DMODEL * DMODEL * 2);
    const size_t w1B = al((size_t)NLAYER * FFDIM * DMODEL * 2);
    const size_t w2B = al((size_t)NLAYER * DMODEL * FFDIM * 2);
    const size_t wB = wqkvB + woB + w1B + w2B;
    const size_t xbB = al((size_t)NPTS * DMODEL * 2);
    const size_t hB = al((size_t)NPTS * DMODEL * 4);

    // choose mode + chunk size to fit ws_size
    int CH = 0;
    bool modeA = true;
    for (int ch = 16384; ch >= 128; ch >>= 1) {
        size_t need = sortB + wB + xbB + hB + al((size_t)ch * 4096) + al((size_t)ch * 1024) + 65536;
        if (need <= ws_size) { CH = ch; modeA = true; break; }
    }
    if (!CH) {
        for (int ch = 16384; ch >= 128; ch >>= 1) {
            size_t need = sortB + wB + xbB + al((size_t)ch * 4096) + al((size_t)ch * 1024) + 65536;
            if (need <= ws_size) { CH = ch; modeA = false; break; }
        }
    }
    if (!CH) { CH = 128; modeA = false; }  // nothing fits; best effort

    char* ws = (char*)d_ws;
    size_t off = 0;
    auto alloc = [&](size_t bytes) -> void* {
        void* p = ws + off;
        off += al(bytes);
        return p;
    };
    u32* key0 = (u32*)alloc(NPTS * 4);
    u32* val0 = (u32*)alloc(NPTS * 4);
    u32* key1 = (u32*)alloc(NPTS * 4);
    u32* val1 = (u32*)alloc(NPTS * 4);
    u32* ghist = (u32*)alloc(256 * RG * 4);
    u16* wqkv_b = (u16*)alloc((size_t)NLAYER * 3 * DMODEL * DMODEL * 2);
    u16* wo_b = (u16*)alloc((size_t)NLAYER * DMODEL * DMODEL * 2);
    u16* w1_b = (u16*)alloc((size_t)NLAYER * FFDIM * DMODEL * 2);
    u16* w2_b = (u16*)alloc((size_t)NLAYER * DMODEL * FFDIM * 2);
    u16* xb = (u16*)alloc((size_t)NPTS * DMODEL * 2);
    float* h = modeA ? (float*)alloc((size_t)NPTS * DMODEL * 4) : nullptr;
    u16* scratch1 = (u16*)alloc((size_t)CH * 4096);  // qkv (CH*768) + attout (CH*256) | ffn-mid (CH*2048)
    float* tmpc = (float*)alloc((size_t)CH * 1024);  // CH x 256 fp32 delta

    // 1. morton keys
    morton_kernel<<<NPTS / 256, 256, 0, stream>>>(coords, key0, val0);

    // 2. stable radix sort, 3 x 8-bit passes (24-bit keys)
    u32 *ki = key0, *vi = val0, *ko = key1, *vo = val1;
    for (int p = 0; p < 3; ++p) {
        hist_kernel<<<RG, 256, 0, stream>>>(ki, ghist, p * 8);
        scan_kernel<<<1, 1024, 0, stream>>>(ghist);
        scatter_kernel<<<RG, 256, 0, stream>>>(ki, vi, ko, vo, ghist, p * 8);
        u32* t;
        t = ki; ki = ko; ko = t;
        t = vi; vi = vo; vo = t;
    }
    const u32* idx = vi;  // sorted original indices

    // 3. weights -> bf16
    cvt_bf16_kernel<<<(NLAYER * 3 * DMODEL * DMODEL) / 256, 256, 0, stream>>>(Wqkv, wqkv_b, NLAYER * 3 * DMODEL * DMODEL);
    cvt_bf16_kernel<<<(NLAYER * DMODEL * DMODEL) / 256, 256, 0, stream>>>(Wo, wo_b, NLAYER * DMODEL * DMODEL);
    cvt_bf16_kernel<<<(NLAYER * FFDIM * DMODEL) / 256, 256, 0, stream>>>(W1, w1_b, NLAYER * FFDIM * DMODEL);
    cvt_bf16_kernel<<<(NLAYER * DMODEL * FFDIM) / 256, 256, 0, stream>>>(W2, w2_b, NLAYER * DMODEL * FFDIM);

    // 4. gather + PE
    if (modeA)
        gather_pe_kernel<true><<<NPTS / 4, 256, 0, stream>>>(idx, coords, feat, pex, pey, pez, pes, h, xb);
    else
        gather_pe_kernel<false><<<NPTS / 4, 256, 0, stream>>>(idx, coords, feat, pex, pey, pez, pes, nullptr, xb);

    // 5. encoder layers, chunked over rows (CH rows = CH/128 windows per chunk)
    const int nch = NPTS / CH;
    u16* qkvc = scratch1;                     // CH x 768 bf16
    u16* attoutc = scratch1 + (size_t)CH * 768;  // CH x 256 bf16
    u16* midc = scratch1;                     // CH x 2048 bf16 (reuses qkv region)
    for (int l = 0; l < NLAYER; ++l) {
        for (int c = 0; c < nch; ++c) {
            u16* xc = xb + (size_t)c * CH * DMODEL;
            float* hc = modeA ? h + (size_t)c * CH * DMODEL : nullptr;
            // qkv = x @ Wqkv^T + bqkv  -> bf16
            gemm_bt<false, true><<<dim3(CH / 128, (3 * DMODEL) / 128), 256, 0, stream>>>(
                xc, wqkv_b + (size_t)l * 3 * DMODEL * DMODEL, bqkv + (size_t)l * 3 * DMODEL, qkvc,
                CH, 3 * DMODEL, DMODEL);
            // window attention -> attout bf16
            attn_kernel<<<(CH / WSIZE) * NHEAD, WSIZE, 0, stream>>>(qkvc, attoutc);
            // o = attout @ Wo^T + bo -> fp32
            gemm_bt<false, false><<<dim3(CH / 128, DMODEL / 128), 256, 0, stream>>>(
                attoutc, wo_b + (size_t)l * DMODEL * DMODEL, bo + (size_t)l * DMODEL, tmpc,
                CH, DMODEL, DMODEL);
            // h = LN(h + o)
            if (modeA)
                resid_ln_kernel<true, false><<<CH / 4, 256, 0, stream>>>(hc, tmpc, g1 + (size_t)l * DMODEL,
                                                                         be1 + (size_t)l * DMODEL, hc, xc);
            else
                resid_ln_kernel<false, false><<<CH / 4, 256, 0, stream>>>(xc, tmpc, g1 + (size_t)l * DMODEL,
                                                                          be1 + (size_t)l * DMODEL, nullptr, xc);
            // FFN
            gemm_bt<true, true><<<dim3(CH / 128, FFDIM / 128), 256, 0, stream>>>(
                xc, w1_b + (size_t)l * FFDIM * DMODEL, b1 + (size_t)l * FFDIM, midc,
                CH, FFDIM, DMODEL);
            gemm_bt<false, false><<<dim3(CH / 128, DMODEL / 128), 256, 0, stream>>>(
                midc, w2_b + (size_t)l * DMODEL * FFDIM, b2 + (size_t)l * DMODEL, tmpc,
                CH, DMODEL, FFDIM);
            // h = LN(h + ff)
            bool last = (l == NLAYER - 1);
            void* outc = last ? (void*)((float*)d_out + (size_t)c * CH * DMODEL) : (void*)xc;
            if (modeA) {
                if (last)
                    resid_ln_kernel<true, true><<<CH / 4, 256, 0, stream>>>(hc, tmpc, g2 + (size_t)l * DMODEL,
                                                                            be2 + (size_t)l * DMODEL, hc, outc);
                else
                    resid_ln_kernel<true, false><<<CH / 4, 256, 0, stream>>>(hc, tmpc, g2 + (size_t)l * DMODEL,
                                                                             be2 + (size_t)l * DMODEL, hc, outc);
            } else {
                if (last)
                    resid_ln_kernel<false, true><<<CH / 4, 256, 0, stream>>>(xc, tmpc, g2 + (size_t)l * DMODEL,
                                                                             be2 + (size_t)l * DMODEL, nullptr, outc);
                else
                    resid_ln_kernel<false, false><<<CH / 4, 256, 0, stream>>>(xc, tmpc, g2 + (size_t)l * DMODEL,
                                                                              be2 + (size_t)l * DMODEL, nullptr, outc);
            }
        }
    }
}

// Round 5
// 2802.519 us; speedup vs baseline: 1.3673x; 1.3673x over previous
//
#include <hip/hip_runtime.h>

typedef unsigned int u32;
typedef unsigned short u16;

#define NPTS 65536
#define DMODEL 256
#define NHEAD 8
#define DHEAD 32
#define NLAYER 4
#define FFDIM 2048
#define WSIZE 128
#define LNEPS 1e-5f
#define RG 256  // radix sort blocks (chunk = 256 elements each)

// LDS strides (bf16 elems) chosen to avoid systematic bank conflicts
#define KSTR 36
#define VSTR 132
#define PSTR 132

typedef __attribute__((ext_vector_type(8))) short short8;
typedef __attribute__((ext_vector_type(4))) float floatx4;

__device__ __forceinline__ float bf2f(u16 v) {
    u32 u = ((u32)v) << 16;
    float f;
    __builtin_memcpy(&f, &u, 4);
    return f;
}
__device__ __forceinline__ u16 f2bf(float f) {
    u32 u;
    __builtin_memcpy(&u, &f, 4);
    u32 r = (u + 0x7fffu + ((u >> 16) & 1u)) >> 16;
    return (u16)r;
}

__device__ __forceinline__ void gl_lds16(const void* g, void* l) {
    __builtin_amdgcn_global_load_lds((const __attribute__((address_space(1))) u32*)g,
                                     (__attribute__((address_space(3))) u32*)l, 16, 0, 0);
}

// ---------------- Morton keys ----------------
__global__ __launch_bounds__(256) void morton_kernel(const int* __restrict__ coords,
                                                     u32* __restrict__ key, u32* __restrict__ val) {
    int i = blockIdx.x * 256 + threadIdx.x;
    int b = coords[4 * i + 0];
    int x = coords[4 * i + 1];
    int y = coords[4 * i + 2];
    int z = coords[4 * i + 3];
    u32 m = 0;
#pragma unroll
    for (int t = 0; t < 7; ++t) {
        m |= ((u32)((x >> t) & 1) << (3 * t + 2)) | ((u32)((y >> t) & 1) << (3 * t + 1)) |
             ((u32)((z >> t) & 1) << (3 * t));
    }
    key[i] = ((u32)b << 21) | m;
    val[i] = (u32)i;
}

// ---------------- radix sort (stable LSD, 3 x 8-bit) ----------------
__global__ __launch_bounds__(256) void hist_kernel(const u32* __restrict__ key, u32* __restrict__ ghist,
                                                   int shift) {
    __shared__ u32 h[256];
    int tid = threadIdx.x;
    h[tid] = 0;
    __syncthreads();
    u32 k = key[blockIdx.x * 256 + tid];
    atomicAdd(&h[(k >> shift) & 255u], 1u);
    __syncthreads();
    ghist[(size_t)tid * RG + blockIdx.x] = h[tid];  // bucket-major
}

__global__ __launch_bounds__(1024) void scan_kernel(u32* __restrict__ g) {
    // exclusive scan over 256*RG = 65536 entries, single block
    __shared__ u32 part[1024];
    int tid = threadIdx.x;
    u32 loc[64];
    u32 s = 0;
    int base = tid * 64;
#pragma unroll 4
    for (int i = 0; i < 64; ++i) {
        loc[i] = g[base + i];
        s += loc[i];
    }
    part[tid] = s;
    __syncthreads();
    for (int off = 1; off < 1024; off <<= 1) {
        u32 v = (tid >= off) ? part[tid - off] : 0u;
        __syncthreads();
        part[tid] += v;
        __syncthreads();
    }
    u32 run = (tid == 0) ? 0u : part[tid - 1];
#pragma unroll 4
    for (int i = 0; i < 64; ++i) {
        u32 t = loc[i];
        g[base + i] = run;
        run += t;
    }
}

__global__ __launch_bounds__(256) void scatter_kernel(const u32* __restrict__ keyin, const u32* __restrict__ valin,
                                                      u32* __restrict__ keyout, u32* __restrict__ valout,
                                                      const u32* __restrict__ ghist, int shift) {
    __shared__ u32 kk[256];
    __shared__ u32 vv[256];
    int tid = threadIdx.x;
    int gi = blockIdx.x * 256 + tid;
    kk[tid] = keyin[gi];
    vv[tid] = valin[gi];
    __syncthreads();
    u32 b = (kk[tid] >> shift) & 255u;
    int rank = 0;
    for (int s = 0; s < tid; ++s) rank += (((kk[s] >> shift) & 255u) == b) ? 1 : 0;
    u32 dst = ghist[(size_t)b * RG + blockIdx.x] + (u32)rank;
    keyout[dst] = kk[tid];
    valout[dst] = vv[tid];
}

// ---------------- weight fp32 -> bf16 ----------------
__global__ __launch_bounds__(256) void cvt_bf16_kernel(const float* __restrict__ in, u16* __restrict__ out, int n) {
    int i = blockIdx.x * 256 + threadIdx.x;
    if (i < n) out[i] = f2bf(in[i]);
}

// ---------------- gather + positional encodings ----------------
template <bool HF32>
__global__ __launch_bounds__(256) void gather_pe_kernel(const u32* __restrict__ idx, const int* __restrict__ coords,
                                                        const float* __restrict__ feat,
                                                        const float* __restrict__ pex, const float* __restrict__ pey,
                                                        const float* __restrict__ pez, const float* __restrict__ pes,
                                                        float* __restrict__ h, u16* __restrict__ xb) {
    int row = blockIdx.x * 4 + (threadIdx.x >> 6);
    int lane = threadIdx.x & 63;
    int src = (int)idx[row];
    int cx = coords[4 * src + 1];
    int cy = coords[4 * src + 2];
    int cz = coords[4 * src + 3];
    int c = lane * 4;
    float4 f = *(const float4*)(feat + (size_t)src * DMODEL + c);
    float4 px = *(const float4*)(pex + (size_t)cx * DMODEL + c);
    float4 py = *(const float4*)(pey + (size_t)cy * DMODEL + c);
    float4 pz = *(const float4*)(pez + (size_t)cz * DMODEL + c);
    float4 ps = *(const float4*)(pes + (size_t)1 * DMODEL + c);  // pe_s[1]
    float4 r;
    r.x = f.x + px.x + py.x + pz.x + ps.x;
    r.y = f.y + px.y + py.y + pz.y + ps.y;
    r.z = f.z + px.z + py.z + pz.z + ps.z;
    r.w = f.w + px.w + py.w + pz.w + ps.w;
    if (HF32) *(float4*)(h + (size_t)row * DMODEL + c) = r;
    ushort4 o;
    o.x = f2bf(r.x);
    o.y = f2bf(r.y);
    o.z = f2bf(r.z);
    o.w = f2bf(r.w);
    *(ushort4*)(xb + (size_t)row * DMODEL + c) = o;
}

// ---------------- GEMM: C = A @ W^T + bias  (A: MxK bf16, W: OxK bf16) ----------------
// m97-style: 128x128 tile, BK=64, 4 waves each computing 64x64 via 4x4 of 16x16x32 MFMA.
template <bool RELU, bool BF16OUT>
__global__ __launch_bounds__(256) void gemm_bt(const u16* __restrict__ A, const u16* __restrict__ W,
                                               const float* __restrict__ bias, void* __restrict__ Cout,
                                               int M, int O, int K) {
    __shared__ __align__(16) u16 lA[128 * 64];
    __shared__ __align__(16) u16 lB[128 * 64];
    const int tid = threadIdx.x;
    const int lane = tid & 63;
    const int wave = tid >> 6;
    const int wr = wave >> 1;
    const int wc = wave & 1;
    const int quad = lane >> 4;
    const int l16 = lane & 15;
    const size_t row0 = (size_t)blockIdx.x * 128;
    const size_t col0 = (size_t)blockIdx.y * 128;
    floatx4 acc[4][4] = {};
    const u16* Abase = A + row0 * (size_t)K;
    const u16* Wbase = W + col0 * (size_t)K;

    for (int k0 = 0; k0 < K; k0 += 64) {
        __syncthreads();
#pragma unroll
        for (int it = 0; it < 4; ++it) {
            int cidx = tid + it * 256;   // chunk 0..1023; each chunk = 8 bf16 = 16B
            int r = cidx >> 3;           // row 0..127
            int cc = (cidx & 7) << 3;    // col 0..56 step 8
            gl_lds16(Abase + (size_t)r * K + k0 + cc, &lA[cidx * 8]);
            gl_lds16(Wbase + (size_t)r * K + k0 + cc, &lB[cidx * 8]);
        }
        __syncthreads();
#pragma unroll
        for (int kk = 0; kk < 64; kk += 32) {
            short8 af[4], bf[4];
#pragma unroll
            for (int r = 0; r < 4; ++r)
                af[r] = *(const short8*)&lA[(wr * 64 + r * 16 + l16) * 64 + kk + quad * 8];
#pragma unroll
            for (int c = 0; c < 4; ++c)
                bf[c] = *(const short8*)&lB[(wc * 64 + c * 16 + l16) * 64 + kk + quad * 8];
#pragma unroll
            for (int r = 0; r < 4; ++r)
#pragma unroll
                for (int c = 0; c < 4; ++c)
                    acc[r][c] = __builtin_amdgcn_mfma_f32_16x16x32_bf16(af[r], bf[c], acc[r][c], 0, 0, 0);
        }
    }

#pragma unroll
    for (int r = 0; r < 4; ++r) {
#pragma unroll
        for (int c = 0; c < 4; ++c) {
            size_t col = col0 + wc * 64 + c * 16 + l16;
            float bv = bias[col];
#pragma unroll
            for (int reg = 0; reg < 4; ++reg) {
                size_t row = row0 + wr * 64 + r * 16 + quad * 4 + reg;
                float v = acc[r][c][reg] + bv;
                if (RELU) v = fmaxf(v, 0.f);
                if (BF16OUT)
                    ((u16*)Cout)[row * O + col] = f2bf(v);
                else
                    ((float*)Cout)[row * O + col] = v;
            }
        }
    }
}

// ---------------- window attention, MFMA (one block = one (window, head)) ----------------
// 2 waves x 64 query rows. S = Q@K^T via mfma (K staged LDS, stride 36);
// softmax in registers (per-lane over 8 col-tiles + shfl_xor over l16);
// unnormalized exp(P) -> LDS bf16 (C-layout -> A-layout transform); O = P@V via
// mfma with V staged transposed (stride 132); 1/sum applied in epilogue.
__global__ __launch_bounds__(128) void attn_kernel(const u16* __restrict__ qkv, u16* __restrict__ outb) {
    const int wh = blockIdx.x;
    const int w = wh >> 3;   // window index within chunk
    const int h = wh & 7;
    const int tid = threadIdx.x;
    const int wave = tid >> 6;
    const int lane = tid & 63;
    const int quad = lane >> 4;
    const int l16 = lane & 15;
    __shared__ __align__(16) u16 lK[128 * KSTR];
    __shared__ __align__(16) u16 lVt[32 * VSTR];
    __shared__ __align__(16) u16 lP[128 * PSTR];
    const u16* base = qkv + (size_t)w * WSIZE * (3 * DMODEL);

    // cooperative staging: thread t handles token t
    {
        const u16* krow = base + (size_t)tid * (3 * DMODEL) + DMODEL + h * DHEAD;
        const u16* vrow = base + (size_t)tid * (3 * DMODEL) + 2 * DMODEL + h * DHEAD;
#pragma unroll
        for (int p = 0; p < 4; ++p)
            *(short8*)&lK[tid * KSTR + p * 8] = *(const short8*)(krow + p * 8);
        u16 varr[32];
#pragma unroll
        for (int p = 0; p < 4; ++p)
            *(short8*)&varr[p * 8] = *(const short8*)(vrow + p * 8);
#pragma unroll
        for (int d = 0; d < DHEAD; ++d) lVt[d * VSTR + tid] = varr[d];
    }
    // Q fragments direct from global (A-frag: row = l16 within m-tile, k = quad*8..+8)
    short8 af[4];
#pragma unroll
    for (int mi = 0; mi < 4; ++mi)
        af[mi] = *(const short8*)(base + (size_t)(wave * 64 + mi * 16 + l16) * (3 * DMODEL) + h * DHEAD + quad * 8);
    __syncthreads();

    // S = Q @ K^T : 4 m-tiles x 8 n-tiles, K-dim = 32 = one mfma step
    floatx4 acc[4][8] = {};
#pragma unroll
    for (int ni = 0; ni < 8; ++ni) {
        short8 bk = *(const short8*)&lK[(ni * 16 + l16) * KSTR + quad * 8];
#pragma unroll
        for (int mi = 0; mi < 4; ++mi)
            acc[mi][ni] = __builtin_amdgcn_mfma_f32_16x16x32_bf16(af[mi], bk, acc[mi][ni], 0, 0, 0);
    }

    // softmax over each row (row = wave*64 + mi*16 + quad*4 + reg; cols = ni*16 + l16)
    const float scale = 0.17677669529663687f;  // 1/sqrt(32)
    float inv[4][4];
#pragma unroll
    for (int mi = 0; mi < 4; ++mi) {
#pragma unroll
        for (int reg = 0; reg < 4; ++reg) {
            float m = acc[mi][0][reg];
#pragma unroll
            for (int ni = 1; ni < 8; ++ni) m = fmaxf(m, acc[mi][ni][reg]);
            m = fmaxf(m, __shfl_xor(m, 1, 64));
            m = fmaxf(m, __shfl_xor(m, 2, 64));
            m = fmaxf(m, __shfl_xor(m, 4, 64));
            m = fmaxf(m, __shfl_xor(m, 8, 64));
            float e[8];
            float sum = 0.f;
#pragma unroll
            for (int ni = 0; ni < 8; ++ni) {
                e[ni] = __expf((acc[mi][ni][reg] - m) * scale);
                sum += e[ni];
            }
            sum += __shfl_xor(sum, 1, 64);
            sum += __shfl_xor(sum, 2, 64);
            sum += __shfl_xor(sum, 4, 64);
            sum += __shfl_xor(sum, 8, 64);
            inv[mi][reg] = 1.f / sum;
            int row = wave * 64 + mi * 16 + quad * 4 + reg;
#pragma unroll
            for (int ni = 0; ni < 8; ++ni) lP[row * PSTR + ni * 16 + l16] = f2bf(e[ni]);
        }
    }
    // same-wave LDS write->read dependency: compiler inserts lgkmcnt waits (no barrier:
    // each wave reads only its own 64 rows of lP)

    // O = P @ V : 4 m-tiles x 2 n-tiles, K-dim = 128 (4 mfma steps)
    floatx4 acc2[4][2] = {};
#pragma unroll
    for (int kt = 0; kt < 4; ++kt) {
        short8 pa[4];
#pragma unroll
        for (int mi = 0; mi < 4; ++mi)
            pa[mi] = *(const short8*)&lP[(wave * 64 + mi * 16 + l16) * PSTR + kt * 32 + quad * 8];
#pragma unroll
        for (int c = 0; c < 2; ++c) {
            short8 bv = *(const short8*)&lVt[(c * 16 + l16) * VSTR + kt * 32 + quad * 8];
#pragma unroll
            for (int mi = 0; mi < 4; ++mi)
                acc2[mi][c] = __builtin_amdgcn_mfma_f32_16x16x32_bf16(pa[mi], bv, acc2[mi][c], 0, 0, 0);
        }
    }

    // epilogue: normalize and store bf16
#pragma unroll
    for (int mi = 0; mi < 4; ++mi) {
#pragma unroll
        for (int c = 0; c < 2; ++c) {
#pragma unroll
            for (int reg = 0; reg < 4; ++reg) {
                int row = wave * 64 + mi * 16 + quad * 4 + reg;
                outb[(size_t)(w * WSIZE + row) * DMODEL + h * DHEAD + c * 16 + l16] =
                    f2bf(acc2[mi][c][reg] * inv[mi][reg]);
            }
        }
    }
}

// ---------------- residual add + LayerNorm (chunk-local, pointers pre-offset) ----------------
// HF32: residual stream held in fp32 (hin/hout) vs bf16 (hin bf16, no hout)
// OUTF32: normalized output written as fp32 (final layer -> d_out) vs bf16
template <bool HF32, bool OUTF32>
__global__ __launch_bounds__(256) void resid_ln_kernel(const void* __restrict__ hin, const float* __restrict__ delta,
                                                       const float* __restrict__ g, const float* __restrict__ b,
                                                       float* __restrict__ hout, void* __restrict__ nout) {
    int row = blockIdx.x * 4 + (threadIdx.x >> 6);
    int lane = threadIdx.x & 63;
    int c = lane * 4;
    float4 x;
    if (HF32) {
        x = *(const float4*)((const float*)hin + (size_t)row * DMODEL + c);
    } else {
        ushort4 hv = *(const ushort4*)((const u16*)hin + (size_t)row * DMODEL + c);
        x.x = bf2f(hv.x);
        x.y = bf2f(hv.y);
        x.z = bf2f(hv.z);
        x.w = bf2f(hv.w);
    }
    float4 d = *(const float4*)(delta + (size_t)row * DMODEL + c);
    x.x += d.x;
    x.y += d.y;
    x.z += d.z;
    x.w += d.w;
    float s = x.x + x.y + x.z + x.w;
#pragma unroll
    for (int off = 32; off > 0; off >>= 1) s += __shfl_xor(s, off, 64);
    float mu = s * (1.f / 256.f);
    float d0 = x.x - mu, d1 = x.y - mu, d2 = x.z - mu, d3 = x.w - mu;
    float vs = d0 * d0 + d1 * d1 + d2 * d2 + d3 * d3;
#pragma unroll
    for (int off = 32; off > 0; off >>= 1) vs += __shfl_xor(vs, off, 64);
    float rs = rsqrtf(vs * (1.f / 256.f) + LNEPS);
    float4 gg = *(const float4*)(g + c);
    float4 bb = *(const float4*)(b + c);
    float4 y;
    y.x = d0 * rs * gg.x + bb.x;
    y.y = d1 * rs * gg.y + bb.y;
    y.z = d2 * rs * gg.z + bb.z;
    y.w = d3 * rs * gg.w + bb.w;
    if (HF32) *(float4*)(hout + (size_t)row * DMODEL + c) = y;
    if (OUTF32) {
        *(float4*)((float*)nout + (size_t)row * DMODEL + c) = y;
    } else {
        ushort4 o;
        o.x = f2bf(y.x);
        o.y = f2bf(y.y);
        o.z = f2bf(y.z);
        o.w = f2bf(y.w);
        *(ushort4*)((u16*)nout + (size_t)row * DMODEL + c) = o;
    }
}

// ---------------- launch ----------------
extern "C" void kernel_launch(void* const* d_in, const int* in_sizes, int n_in,
                              void* d_out, int out_size, void* d_ws, size_t ws_size,
                              hipStream_t stream) {
    (void)in_sizes;
    (void)n_in;
    (void)out_size;
    const int* coords = (const int*)d_in[0];
    const float* feat = (const float*)d_in[1];
    const float* pex = (const float*)d_in[2];
    const float* pey = (const float*)d_in[3];
    const float* pez = (const float*)d_in[4];
    const float* pes = (const float*)d_in[5];
    const float* Wqkv = (const float*)d_in[6];
    const float* bqkv = (const float*)d_in[7];
    const float* Wo = (const float*)d_in[8];
    const float* bo = (const float*)d_in[9];
    const float* W1 = (const float*)d_in[10];
    const float* b1 = (const float*)d_in[11];
    const float* W2 = (const float*)d_in[12];
    const float* b2 = (const float*)d_in[13];
    const float* g1 = (const float*)d_in[14];
    const float* be1 = (const float*)d_in[15];
    const float* g2 = (const float*)d_in[16];
    const float* be2 = (const float*)d_in[17];

    auto al = [](size_t x) { return (x + 255) & ~(size_t)255; };
    // fixed allocations
    const size_t sortB = 4 * al((size_t)NPTS * 4) + al((size_t)256 * RG * 4);
    const size_t wqkvB = al((size_t)NLAYER * 3 * DMODEL * DMODEL * 2);
    const size_t woB = al((size_t)NLAYER * DMODEL * DMODEL * 2);
    const size_t w1B = al((size_t)NLAYER * FFDIM * DMODEL * 2);
    const size_t w2B = al((size_t)NLAYER * DMODEL * FFDIM * 2);
    const size_t wB = wqkvB + woB + w1B + w2B;
    const size_t xbB = al((size_t)NPTS * DMODEL * 2);
    const size_t hB = al((size_t)NPTS * DMODEL * 4);

    // choose mode + chunk size to fit ws_size
    int CH = 0;
    bool modeA = true;
    for (int ch = 16384; ch >= 128; ch >>= 1) {
        size_t need = sortB + wB + xbB + hB + al((size_t)ch * 4096) + al((size_t)ch * 1024) + 65536;
        if (need <= ws_size) { CH = ch; modeA = true; break; }
    }
    if (!CH) {
        for (int ch = 16384; ch >= 128; ch >>= 1) {
            size_t need = sortB + wB + xbB + al((size_t)ch * 4096) + al((size_t)ch * 1024) + 65536;
            if (need <= ws_size) { CH = ch; modeA = false; break; }
        }
    }
    if (!CH) { CH = 128; modeA = false; }  // nothing fits; best effort

    char* ws = (char*)d_ws;
    size_t off = 0;
    auto alloc = [&](size_t bytes) -> void* {
        void* p = ws + off;
        off += al(bytes);
        return p;
    };
    u32* key0 = (u32*)alloc(NPTS * 4);
    u32* val0 = (u32*)alloc(NPTS * 4);
    u32* key1 = (u32*)alloc(NPTS * 4);
    u32* val1 = (u32*)alloc(NPTS * 4);
    u32* ghist = (u32*)alloc(256 * RG * 4);
    u16* wqkv_b = (u16*)alloc((size_t)NLAYER * 3 * DMODEL * DMODEL * 2);
    u16* wo_b = (u16*)alloc((size_t)NLAYER * DMODEL * DMODEL * 2);
    u16* w1_b = (u16*)alloc((size_t)NLAYER * FFDIM * DMODEL * 2);
    u16* w2_b = (u16*)alloc((size_t)NLAYER * DMODEL * FFDIM * 2);
    u16* xb = (u16*)alloc((size_t)NPTS * DMODEL * 2);
    float* h = modeA ? (float*)alloc((size_t)NPTS * DMODEL * 4) : nullptr;
    u16* scratch1 = (u16*)alloc((size_t)CH * 4096);  // qkv (CH*768) + attout (CH*256) | ffn-mid (CH*2048)
    float* tmpc = (float*)alloc((size_t)CH * 1024);  // CH x 256 fp32 delta

    // 1. morton keys
    morton_kernel<<<NPTS / 256, 256, 0, stream>>>(coords, key0, val0);

    // 2. stable radix sort, 3 x 8-bit passes (24-bit keys)
    u32 *ki = key0, *vi = val0, *ko = key1, *vo = val1;
    for (int p = 0; p < 3; ++p) {
        hist_kernel<<<RG, 256, 0, stream>>>(ki, ghist, p * 8);
        scan_kernel<<<1, 1024, 0, stream>>>(ghist);
        scatter_kernel<<<RG, 256, 0, stream>>>(ki, vi, ko, vo, ghist, p * 8);
        u32* t;
        t = ki; ki = ko; ko = t;
        t = vi; vi = vo; vo = t;
    }
    const u32* idx = vi;  // sorted original indices

    // 3. weights -> bf16
    cvt_bf16_kernel<<<(NLAYER * 3 * DMODEL * DMODEL) / 256, 256, 0, stream>>>(Wqkv, wqkv_b, NLAYER * 3 * DMODEL * DMODEL);
    cvt_bf16_kernel<<<(NLAYER * DMODEL * DMODEL) / 256, 256, 0, stream>>>(Wo, wo_b, NLAYER * DMODEL * DMODEL);
    cvt_bf16_kernel<<<(NLAYER * FFDIM * DMODEL) / 256, 256, 0, stream>>>(W1, w1_b, NLAYER * FFDIM * DMODEL);
    cvt_bf16_kernel<<<(NLAYER * DMODEL * FFDIM) / 256, 256, 0, stream>>>(W2, w2_b, NLAYER * DMODEL * FFDIM);

    // 4. gather + PE
    if (modeA)
        gather_pe_kernel<true><<<NPTS / 4, 256, 0, stream>>>(idx, coords, feat, pex, pey, pez, pes, h, xb);
    else
        gather_pe_kernel<false><<<NPTS / 4, 256, 0, stream>>>(idx, coords, feat, pex, pey, pez, pes, nullptr, xb);

    // 5. encoder layers, chunked over rows (CH rows = CH/128 windows per chunk)
    const int nch = NPTS / CH;
    u16* qkvc = scratch1;                     // CH x 768 bf16
    u16* attoutc = scratch1 + (size_t)CH * 768;  // CH x 256 bf16
    u16* midc = scratch1;                     // CH x 2048 bf16 (reuses qkv region)
    for (int l = 0; l < NLAYER; ++l) {
        for (int c = 0; c < nch; ++c) {
            u16* xc = xb + (size_t)c * CH * DMODEL;
            float* hc = modeA ? h + (size_t)c * CH * DMODEL : nullptr;
            // qkv = x @ Wqkv^T + bqkv  -> bf16
            gemm_bt<false, true><<<dim3(CH / 128, (3 * DMODEL) / 128), 256, 0, stream>>>(
                xc, wqkv_b + (size_t)l * 3 * DMODEL * DMODEL, bqkv + (size_t)l * 3 * DMODEL, qkvc,
                CH, 3 * DMODEL, DMODEL);
            // window attention (MFMA) -> attout bf16
            attn_kernel<<<(CH / WSIZE) * NHEAD, 128, 0, stream>>>(qkvc, attoutc);
            // o = attout @ Wo^T + bo -> fp32
            gemm_bt<false, false><<<dim3(CH / 128, DMODEL / 128), 256, 0, stream>>>(
                attoutc, wo_b + (size_t)l * DMODEL * DMODEL, bo + (size_t)l * DMODEL, tmpc,
                CH, DMODEL, DMODEL);
            // h = LN(h + o)
            if (modeA)
                resid_ln_kernel<true, false><<<CH / 4, 256, 0, stream>>>(hc, tmpc, g1 + (size_t)l * DMODEL,
                                                                         be1 + (size_t)l * DMODEL, hc, xc);
            else
                resid_ln_kernel<false, false><<<CH / 4, 256, 0, stream>>>(xc, tmpc, g1 + (size_t)l * DMODEL,
                                                                          be1 + (size_t)l * DMODEL, nullptr, xc);
            // FFN
            gemm_bt<true, true><<<dim3(CH / 128, FFDIM / 128), 256, 0, stream>>>(
                xc, w1_b + (size_t)l * FFDIM * DMODEL, b1 + (size_t)l * FFDIM, midc,
                CH, FFDIM, DMODEL);
            gemm_bt<false, false><<<dim3(CH / 128, DMODEL / 128), 256, 0, stream>>>(
                midc, w2_b + (size_t)l * DMODEL * FFDIM, b2 + (size_t)l * DMODEL, tmpc,
                CH, DMODEL, FFDIM);
            // h = LN(h + ff)
            bool last = (l == NLAYER - 1);
            void* outc = last ? (void*)((float*)d_out + (size_t)c * CH * DMODEL) : (void*)xc;
            if (modeA) {
                if (last)
                    resid_ln_kernel<true, true><<<CH / 4, 256, 0, stream>>>(hc, tmpc, g2 + (size_t)l * DMODEL,
                                                                            be2 + (size_t)l * DMODEL, hc, outc);
                else
                    resid_ln_kernel<true, false><<<CH / 4, 256, 0, stream>>>(hc, tmpc, g2 + (size_t)l * DMODEL,
                                                                             be2 + (size_t)l * DMODEL, hc, outc);
            } else {
                if (last)
                    resid_ln_kernel<false, true><<<CH / 4, 256, 0, stream>>>(xc, tmpc, g2 + (size_t)l * DMODEL,
                                                                             be2 + (size_t)l * DMODEL, nullptr, outc);
                else
                    resid_ln_kernel<false, false><<<CH / 4, 256, 0, stream>>>(xc, tmpc, g2 + (size_t)l * DMODEL,
                                                                              be2 + (size_t)l * DMODEL, nullptr, outc);
            }
        }
    }
}